// Round 11
// baseline (12756.081 us; speedup 1.0000x reference)
//
#include <hip/hip_runtime.h>
#include <math.h>
#include <stdint.h>

#define TT   512
#define BB   64
#define EMBD 300
#define NU   512
#define G3   1536   // 3*UNITS

static constexpr size_t XW_FLOATS = (size_t)2 * TT * BB * G3;   // 100,663,296
static constexpr size_t HB_FLOATS = (size_t)2 * 2 * BB * NU;    //     131,072

// ------------- embedding gather + input GEMM: xw[dir][t][b][c] -------------
__global__ __launch_bounds__(256) void k_input_gemm(
    const int* __restrict__ tokens, const float* __restrict__ emb,
    const float* __restrict__ Wf, const float* __restrict__ bf,
    const float* __restrict__ Wb, const float* __restrict__ bb,
    float* __restrict__ xw) {
  __shared__ float As[8][72];   // [k][b]
  __shared__ float Bs[8][64];   // [k][n]
  __shared__ int tok[64];
  const int t = blockIdx.y;
  const int n0 = blockIdx.x * 64;
  const int dir = blockIdx.z;
  const float* W = dir ? Wb : Wf;
  const float* bias = dir ? bb : bf;           // row 0 = input bias
  float* out = xw + (size_t)dir * TT * BB * G3;
  const int tid = threadIdx.x;
  if (tid < 64) tok[tid] = tokens[(size_t)tid * TT + t];
  __syncthreads();
  const int tx = tid & 15, ty = tid >> 4;
  float4 c0 = {0,0,0,0}, c1 = {0,0,0,0}, c2 = {0,0,0,0}, c3 = {0,0,0,0};
  for (int kc = 0; kc < 38; ++kc) {
    const int k0 = kc * 8;
    if (tid < 128) {
      int kb = tid >> 4, nq = (tid & 15) * 4;
      float4 v = {0,0,0,0};
      if (k0 + kb < EMBD) v = *(const float4*)(W + (size_t)(k0 + kb) * G3 + n0 + nq);
      *(float4*)&Bs[kb][nq] = v;
    } else {
      int th = tid - 128;
      int b = th >> 1, kh = (th & 1) * 4;
      float4 v = {0,0,0,0};
      if (k0 + kh + 4 <= EMBD) v = *(const float4*)(emb + (size_t)tok[b] * EMBD + k0 + kh);
      As[kh + 0][b] = v.x; As[kh + 1][b] = v.y; As[kh + 2][b] = v.z; As[kh + 3][b] = v.w;
    }
    __syncthreads();
    #pragma unroll
    for (int kb = 0; kb < 8; ++kb) {
      float4 bv = *(const float4*)&Bs[kb][tx * 4];
      float4 av = *(const float4*)&As[kb][ty * 4];
      c0.x = fmaf(av.x, bv.x, c0.x); c0.y = fmaf(av.x, bv.y, c0.y);
      c0.z = fmaf(av.x, bv.z, c0.z); c0.w = fmaf(av.x, bv.w, c0.w);
      c1.x = fmaf(av.y, bv.x, c1.x); c1.y = fmaf(av.y, bv.y, c1.y);
      c1.z = fmaf(av.y, bv.z, c1.z); c1.w = fmaf(av.y, bv.w, c1.w);
      c2.x = fmaf(av.z, bv.x, c2.x); c2.y = fmaf(av.z, bv.y, c2.y);
      c2.z = fmaf(av.z, bv.z, c2.z); c2.w = fmaf(av.z, bv.w, c2.w);
      c3.x = fmaf(av.w, bv.x, c3.x); c3.y = fmaf(av.w, bv.y, c3.y);
      c3.z = fmaf(av.w, bv.z, c3.z); c3.w = fmaf(av.w, bv.w, c3.w);
    }
    __syncthreads();
  }
  float4 bi = *(const float4*)(bias + n0 + tx * 4);
  size_t base = ((size_t)t * BB + (size_t)ty * 4) * G3 + n0 + tx * 4;
  float4 o;
  o.x = c0.x + bi.x; o.y = c0.y + bi.y; o.z = c0.z + bi.z; o.w = c0.w + bi.w;
  *(float4*)(out + base) = o;
  o.x = c1.x + bi.x; o.y = c1.y + bi.y; o.z = c1.z + bi.z; o.w = c1.w + bi.w;
  *(float4*)(out + base + G3) = o;
  o.x = c2.x + bi.x; o.y = c2.y + bi.y; o.z = c2.z + bi.z; o.w = c2.w + bi.w;
  *(float4*)(out + base + 2 * G3) = o;
  o.x = c3.x + bi.x; o.y = c3.y + bi.y; o.z = c3.z + bi.z; o.w = c3.w + bi.w;
  *(float4*)(out + base + 3 * G3) = o;
}

// --------------------------- persistent GRU scan v12 ---------------------------
// Sync MECHANISM = v1/v8/v9 (release fetch_add + poll; the only mechanism that
// passes). Sync STRUCTURE cut from 4 barriers/step to 2:
//  * hprev in a REGISTER (v2/v4-proven) -> epilogue no longer reads hS ->
//    reload cannot race the epilogue -> post-drain and post-poll barriers die.
//  * per-WAVE release: each of the 4 epilogue waves fetch_adds RELEASE
//    (target 64/step). vmcnt is per-wave, so each release publishes exactly
//    its own wave's h stores; issues at wave arrival (no block-wide drain).
//  * per-wave poll (waves 0-3): same-address wave load = 1 broadcast request,
//    s_sleep(1) throttle; each wave reloads its 16KB share immediately after
//    its own poll exits. Waves 4-7 go straight to the end-of-step barrier.
// Barriers/step: sync1 (red handoff) + sync2 (reload -> next compute). Done.
// Arithmetic bit-identical to v9 (absmax 9.77e-4).
__global__ __launch_bounds__(512, 1) void k_gru(
    const float* __restrict__ xw,
    const float* __restrict__ Uf, const float* __restrict__ Ub,
    const float* __restrict__ bf, const float* __restrict__ bb,
    float* __restrict__ hbuf, int* __restrict__ ctr,
    float* __restrict__ out, float* __restrict__ state) {
  __shared__ float hS[8][NU];           // 16KB: h for this block's 8 batches
  __shared__ float red[3][8][16][32];   // 48KB: [gate][batch][ksplit][unit]
  const int wg = blockIdx.x;
  const int dir = wg >> 7;
  const int bblk = (wg >> 4) & 7;
  const int ublk = wg & 15;
  const int u0 = ublk * 32, b0 = bblk * 8;
  const int gid = dir * 8 + bblk;
  int* gctr = ctr + gid * 32;          // 128B-spaced counters (v1 layout)
  const int tid = threadIdx.x;
  const int u  = tid & 31;             // unit within slice (compute phase)
  const int ks = tid >> 5;             // ksplit 0..15 (32 k each)
  const int kb0 = ks * 32;
  const float* xwd = xw + (size_t)dir * TT * BB * G3;
  const float* U = dir ? Ub : Uf;      // [k][c], c = gate*512 + unit
  const float* br = (dir ? bb : bf) + G3;   // row 1 = recurrent bias
  float* hb = hbuf + (size_t)dir * 2 * BB * NU;

  // ---- preload U slice (k in [kb0,kb0+32), col u0+u) into regs ----
  float Uz_r[32], Ur_r[32], Uh_r[32];
  #pragma unroll
  for (int kk = 0; kk < 32; ++kk) {
    const float* row = U + (size_t)(kb0 + kk) * G3 + u0 + u;
    Uz_r[kk] = row[0];
    Ur_r[kk] = row[512];
    Uh_r[kk] = row[1024];
  }

  // epilogue identity (tid < 256); hprev lives in a REGISTER (h0 = 0)
  const int eb = (tid >> 5) & 7, eu = tid & 31;
  const int bg = b0 + eb;
  const float brz = br[u0 + eu], brr = br[512 + u0 + eu], brh = br[1024 + u0 + eu];
  float xz = 0.f, xr = 0.f, xh = 0.f, hprev = 0.f;
  if (tid < 256) {
    const int t0 = dir ? (TT - 1) : 0;
    const float* xp = xwd + ((size_t)t0 * BB + bg) * G3 + u0 + eu;
    xz = xp[0]; xr = xp[512]; xh = xp[1024];
  }

  float* hflat = &hS[0][0];
  #pragma unroll
  for (int j = 0; j < 8; ++j) hflat[tid + j * 512] = 0.f;   // h0 = 0
  __syncthreads();

  for (int s = 0; s < TT; ++s) {
    // ---- PIN: read-write asm each iteration (kept from v9; passed) ----
    #define PIN8(A, i) asm volatile("" : \
        "+v"(A[(i)+0]), "+v"(A[(i)+1]), "+v"(A[(i)+2]), "+v"(A[(i)+3]), \
        "+v"(A[(i)+4]), "+v"(A[(i)+5]), "+v"(A[(i)+6]), "+v"(A[(i)+7]))
    PIN8(Uz_r, 0); PIN8(Uz_r, 8); PIN8(Uz_r, 16); PIN8(Uz_r, 24);
    PIN8(Ur_r, 0); PIN8(Ur_r, 8); PIN8(Ur_r, 16); PIN8(Ur_r, 24);
    PIN8(Uh_r, 0); PIN8(Uh_r, 8); PIN8(Uh_r, 16); PIN8(Uh_r, 24);
    #undef PIN8

    const int t = dir ? (TT - 1 - s) : s;
    float az[8], ar[8], ah[8];
    #pragma unroll
    for (int b = 0; b < 8; ++b) { az[b] = 0.f; ar[b] = 0.f; ah[b] = 0.f; }
    #pragma unroll
    for (int q = 0; q < 8; ++q) {
      #pragma unroll
      for (int b = 0; b < 8; ++b) {
        float4 hv = *(const float4*)&hS[b][kb0 + q * 4];   // 2-addr broadcast
        az[b] = fmaf(Uz_r[q*4+0], hv.x, az[b]); az[b] = fmaf(Uz_r[q*4+1], hv.y, az[b]);
        az[b] = fmaf(Uz_r[q*4+2], hv.z, az[b]); az[b] = fmaf(Uz_r[q*4+3], hv.w, az[b]);
        ar[b] = fmaf(Ur_r[q*4+0], hv.x, ar[b]); ar[b] = fmaf(Ur_r[q*4+1], hv.y, ar[b]);
        ar[b] = fmaf(Ur_r[q*4+2], hv.z, ar[b]); ar[b] = fmaf(Ur_r[q*4+3], hv.w, ar[b]);
        ah[b] = fmaf(Uh_r[q*4+0], hv.x, ah[b]); ah[b] = fmaf(Uh_r[q*4+1], hv.y, ah[b]);
        ah[b] = fmaf(Uh_r[q*4+2], hv.z, ah[b]); ah[b] = fmaf(Uh_r[q*4+3], hv.w, ah[b]);
      }
    }
    #pragma unroll
    for (int b = 0; b < 8; ++b) {
      red[0][b][ks][u] = az[b];
      red[1][b][ks][u] = ar[b];
      red[2][b][ks][u] = ah[b];
    }
    __syncthreads();                       // sync1: red handoff
    float hn = 0.f;
    if (tid < 256) {
      float rz = 0.f, rr = 0.f, rh = 0.f;
      #pragma unroll
      for (int q2 = 0; q2 < 16; ++q2) {
        rz += red[0][eb][q2][eu];
        rr += red[1][eb][q2][eu];
        rh += red[2][eb][q2][eu];
      }
      const float z  = 1.f / (1.f + __expf(-(xz + rz + brz)));
      const float r  = 1.f / (1.f + __expf(-(xr + rr + brr)));
      const float hh = tanhf(xh + r * (rh + brh));
      hn = z * hprev + (1.f - z) * hh;
      hprev = hn;
      // h publish: relaxed agent store (published by this wave's release)
      __hip_atomic_store(hb + ((size_t)(s & 1) * BB + bg) * NU + u0 + eu, hn,
                         __ATOMIC_RELAXED, __HIP_MEMORY_SCOPE_AGENT);
    }
    if (s == TT - 1) {
      if (tid < 256) {
        out[((size_t)bg * TT + t) * 1024 + (size_t)dir * NU + u0 + eu] = hn;
        state[(size_t)bg * 1024 + (size_t)dir * NU + u0 + eu] = hn;
      }
    } else {
      if (tid < 256) {
        // per-WAVE release: drains THIS wave's h stores (vmcnt is per-wave)
        // + wbl2, then the add lands. 4 releases/block, target 64/step.
        if ((tid & 63) == 0) {
          __hip_atomic_fetch_add(gctr, 1, __ATOMIC_RELEASE,
                                 __HIP_MEMORY_SCOPE_AGENT);
        }
        // poll-window work: out store + next-step xw prefetch
        out[((size_t)bg * TT + t) * 1024 + (size_t)dir * NU + u0 + eu] = hn;
        const int tn = dir ? (TT - 2 - s) : (s + 1);
        const float* xp = xwd + ((size_t)tn * BB + bg) * G3 + u0 + eu;
        xz = xp[0]; xr = xp[512]; xh = xp[1024];
        // per-wave poll: same-address wave load = 1 broadcast request/round
        {
          const int target = 64 * (s + 1);
          while (__hip_atomic_load(gctr, __ATOMIC_RELAXED,
                                   __HIP_MEMORY_SCOPE_AGENT) < target) {
            __builtin_amdgcn_s_sleep(1);
          }
        }
        // reload h for our 8 batches (16KB over 256 threads): 8 x u64 each
        const uint64_t* hsrc = (const uint64_t*)(hb + (size_t)(s & 1) * BB * NU);
        #pragma unroll
        for (int j = 0; j < 8; ++j) {
          const int fi = (tid & 255) + j * 256;  // u64 index in [0,2048)
          const int bl = fi >> 8;                // local batch 0..7
          const int k2 = fi & 255;               // u64 within row
          uint64_t v = __hip_atomic_load(hsrc + ((size_t)(b0 + bl) << 8) + k2,
                                         __ATOMIC_RELAXED, __HIP_MEMORY_SCOPE_AGENT);
          *(uint64_t*)&hS[bl][k2 * 2] = v;
        }
      }
      __syncthreads();                     // sync2: reload -> next compute
    }
  }
}

extern "C" void kernel_launch(void* const* d_in, const int* in_sizes, int n_in,
                              void* d_out, int out_size, void* d_ws, size_t ws_size,
                              hipStream_t stream) {
  (void)in_sizes; (void)n_in; (void)out_size; (void)ws_size;
  const int*   tokens = (const int*)d_in[0];
  const float* emb    = (const float*)d_in[1];
  const float* Wf     = (const float*)d_in[2];
  const float* Uf     = (const float*)d_in[3];
  const float* bf     = (const float*)d_in[4];
  const float* Wb     = (const float*)d_in[5];
  const float* Ub     = (const float*)d_in[6];
  const float* bb     = (const float*)d_in[7];
  float* ws = (float*)d_ws;
  float* xw = ws;
  float* hb = ws + XW_FLOATS;
  int*   ctr = (int*)(hb + HB_FLOATS);
  float* out = (float*)d_out;
  float* state = out + (size_t)BB * TT * 1024;

  hipMemsetAsync(ctr, 0, 16 * 32 * sizeof(int), stream);
  hipLaunchKernelGGL(k_input_gemm, dim3(24, 512, 2), dim3(256), 0, stream,
                     tokens, emb, Wf, bf, Wb, bb, xw);
  hipLaunchKernelGGL(k_gru, dim3(256), dim3(512), 0, stream,
                     xw, Uf, Ub, bf, bb, hb, ctr, out, state);
}

// Round 12
// 7300.778 us; speedup vs baseline: 1.7472x; 1.7472x over previous
//
#include <hip/hip_runtime.h>
#include <math.h>
#include <stdint.h>

#define TT   512
#define BB   64
#define EMBD 300
#define NU   512
#define G3   1536   // 3*UNITS

static constexpr size_t XW_FLOATS = (size_t)2 * TT * BB * G3;   // 100,663,296
static constexpr size_t HB_FLOATS = (size_t)2 * 2 * BB * NU;    //     131,072

// ------------- embedding gather + input GEMM: xw[dir][t][b][c] -------------
__global__ __launch_bounds__(256) void k_input_gemm(
    const int* __restrict__ tokens, const float* __restrict__ emb,
    const float* __restrict__ Wf, const float* __restrict__ bf,
    const float* __restrict__ Wb, const float* __restrict__ bb,
    float* __restrict__ xw) {
  __shared__ float As[8][72];   // [k][b]
  __shared__ float Bs[8][64];   // [k][n]
  __shared__ int tok[64];
  const int t = blockIdx.y;
  const int n0 = blockIdx.x * 64;
  const int dir = blockIdx.z;
  const float* W = dir ? Wb : Wf;
  const float* bias = dir ? bb : bf;           // row 0 = input bias
  float* out = xw + (size_t)dir * TT * BB * G3;
  const int tid = threadIdx.x;
  if (tid < 64) tok[tid] = tokens[(size_t)tid * TT + t];
  __syncthreads();
  const int tx = tid & 15, ty = tid >> 4;
  float4 c0 = {0,0,0,0}, c1 = {0,0,0,0}, c2 = {0,0,0,0}, c3 = {0,0,0,0};
  for (int kc = 0; kc < 38; ++kc) {
    const int k0 = kc * 8;
    if (tid < 128) {
      int kb = tid >> 4, nq = (tid & 15) * 4;
      float4 v = {0,0,0,0};
      if (k0 + kb < EMBD) v = *(const float4*)(W + (size_t)(k0 + kb) * G3 + n0 + nq);
      *(float4*)&Bs[kb][nq] = v;
    } else {
      int th = tid - 128;
      int b = th >> 1, kh = (th & 1) * 4;
      float4 v = {0,0,0,0};
      if (k0 + kh + 4 <= EMBD) v = *(const float4*)(emb + (size_t)tok[b] * EMBD + k0 + kh);
      As[kh + 0][b] = v.x; As[kh + 1][b] = v.y; As[kh + 2][b] = v.z; As[kh + 3][b] = v.w;
    }
    __syncthreads();
    #pragma unroll
    for (int kb = 0; kb < 8; ++kb) {
      float4 bv = *(const float4*)&Bs[kb][tx * 4];
      float4 av = *(const float4*)&As[kb][ty * 4];
      c0.x = fmaf(av.x, bv.x, c0.x); c0.y = fmaf(av.x, bv.y, c0.y);
      c0.z = fmaf(av.x, bv.z, c0.z); c0.w = fmaf(av.x, bv.w, c0.w);
      c1.x = fmaf(av.y, bv.x, c1.x); c1.y = fmaf(av.y, bv.y, c1.y);
      c1.z = fmaf(av.y, bv.z, c1.z); c1.w = fmaf(av.y, bv.w, c1.w);
      c2.x = fmaf(av.z, bv.x, c2.x); c2.y = fmaf(av.z, bv.y, c2.y);
      c2.z = fmaf(av.z, bv.z, c2.z); c2.w = fmaf(av.z, bv.w, c2.w);
      c3.x = fmaf(av.w, bv.x, c3.x); c3.y = fmaf(av.w, bv.y, c3.y);
      c3.z = fmaf(av.w, bv.z, c3.z); c3.w = fmaf(av.w, bv.w, c3.w);
    }
    __syncthreads();
  }
  float4 bi = *(const float4*)(bias + n0 + tx * 4);
  size_t base = ((size_t)t * BB + (size_t)ty * 4) * G3 + n0 + tx * 4;
  float4 o;
  o.x = c0.x + bi.x; o.y = c0.y + bi.y; o.z = c0.z + bi.z; o.w = c0.w + bi.w;
  *(float4*)(out + base) = o;
  o.x = c1.x + bi.x; o.y = c1.y + bi.y; o.z = c1.z + bi.z; o.w = c1.w + bi.w;
  *(float4*)(out + base + G3) = o;
  o.x = c2.x + bi.x; o.y = c2.y + bi.y; o.z = c2.z + bi.z; o.w = c2.w + bi.w;
  *(float4*)(out + base + 2 * G3) = o;
  o.x = c3.x + bi.x; o.y = c3.y + bi.y; o.z = c3.z + bi.z; o.w = c3.w + bi.w;
  *(float4*)(out + base + 3 * G3) = o;
}

// --------------------------- persistent GRU scan v13 ---------------------------
// Per-member DATAFLOW sync. Structural fact: ksplit ks reads ONLY
// h[ks*32..ks*32+32) = exactly member ublk==ks's output. So wave w (ksplits
// 2w,2w+1) depends on just members 2w,2w+1 — the all-16 rendezvous (the
// measured ~7.9us/step core of v1/v4/v8/v9) is unnecessary.
// Mechanism (all v4/v1-proven primitives):
//  * publish: relaxed agent h stores; sync2 drains them to L2; tid0 issues a
//    RELEASE-STORE to its PRIVATE slot flags[ublk]=s+1 (16 parallel slots,
//    no RMW chain — v4-proven correct release semantics).
//  * consume: at step s, each wave polls ONLY flags[2w],flags[2w+1] >= s,
//    then reloads its own 2KB window (sc0 agent u64 loads, v1-proven LLC
//    path), LDS-fences (rule #18), and starts FMA — staggered, no barrier.
//  * hprev in a register (v12-proven) -> hS columns [64w,64w+64) are PRIVATE
//    to wave w -> no reload/compute race.
// Barriers/step: sync1 (reduction join) + sync2 (h-store drain). 
// Deadlock-free by time-DAG: block X's step-s release transitively requires
// (via sync1 over all 8 waves = all 16 members' flags >= s) every member's
// step-(s-1) completion — this also kills the parity-overwrite race.
__global__ __launch_bounds__(512, 1) void k_gru(
    const float* __restrict__ xw,
    const float* __restrict__ Uf, const float* __restrict__ Ub,
    const float* __restrict__ bf, const float* __restrict__ bb,
    float* __restrict__ hbuf, int* __restrict__ ctr,
    float* __restrict__ out, float* __restrict__ state) {
  __shared__ float hS[8][NU];           // 16KB; cols [64w,64w+64) private to wave w
  __shared__ float red[3][8][16][32];   // 48KB: [gate][batch][ksplit][unit]
  const int wg = blockIdx.x;
  const int dir = wg >> 7;
  const int bblk = (wg >> 4) & 7;
  const int ublk = wg & 15;
  const int u0 = ublk * 32, b0 = bblk * 8;
  const int gid = dir * 8 + bblk;
  int* flags = ctr + gid * 32;         // 16 member flags, 128B-spaced lines
  const int tid = threadIdx.x;
  const int u  = tid & 31;             // unit within slice (compute phase)
  const int ks = tid >> 5;             // ksplit 0..15 (32 k each)
  const int kb0 = ks * 32;
  const int w    = tid >> 6;           // wave 0..7
  const int lane = tid & 63;
  const float* xwd = xw + (size_t)dir * TT * BB * G3;
  const float* U = dir ? Ub : Uf;      // [k][c], c = gate*512 + unit
  const float* br = (dir ? bb : bf) + G3;   // row 1 = recurrent bias
  float* hb = hbuf + (size_t)dir * 2 * BB * NU;

  // ---- preload U slice (k in [kb0,kb0+32), col u0+u) into regs ----
  float Uz_r[32], Ur_r[32], Uh_r[32];
  #pragma unroll
  for (int kk = 0; kk < 32; ++kk) {
    const float* row = U + (size_t)(kb0 + kk) * G3 + u0 + u;
    Uz_r[kk] = row[0];
    Ur_r[kk] = row[512];
    Uh_r[kk] = row[1024];
  }

  // epilogue identity (tid < 256); hprev lives in a REGISTER (h0 = 0)
  const int eb = (tid >> 5) & 7, eu = tid & 31;
  const int bg = b0 + eb;
  const float brz = br[u0 + eu], brr = br[512 + u0 + eu], brh = br[1024 + u0 + eu];
  float xz = 0.f, xr = 0.f, xh = 0.f, hprev = 0.f;
  if (tid < 256) {
    const int t0 = dir ? (TT - 1) : 0;
    const float* xp = xwd + ((size_t)t0 * BB + bg) * G3 + u0 + eu;
    xz = xp[0]; xr = xp[512]; xh = xp[1024];
  }

  float* hflat = &hS[0][0];
  #pragma unroll
  for (int j = 0; j < 8; ++j) hflat[tid + j * 512] = 0.f;   // h0 = 0
  __syncthreads();

  for (int s = 0; s < TT; ++s) {
    // ---- PIN: read-write asm each iteration (kept from v9; passed) ----
    #define PIN8(A, i) asm volatile("" : \
        "+v"(A[(i)+0]), "+v"(A[(i)+1]), "+v"(A[(i)+2]), "+v"(A[(i)+3]), \
        "+v"(A[(i)+4]), "+v"(A[(i)+5]), "+v"(A[(i)+6]), "+v"(A[(i)+7]))
    PIN8(Uz_r, 0); PIN8(Uz_r, 8); PIN8(Uz_r, 16); PIN8(Uz_r, 24);
    PIN8(Ur_r, 0); PIN8(Ur_r, 8); PIN8(Ur_r, 16); PIN8(Ur_r, 24);
    PIN8(Uh_r, 0); PIN8(Uh_r, 8); PIN8(Uh_r, 16); PIN8(Uh_r, 24);
    #undef PIN8

    const int t = dir ? (TT - 1 - s) : s;

    if (s > 0) {
      // ---- per-wave wait: ONLY the 2 members this wave reads ----
      {
        int f = s;
        for (;;) {
          if (lane < 2)
            f = __hip_atomic_load(flags + 2 * w + lane, __ATOMIC_RELAXED,
                                  __HIP_MEMORY_SCOPE_AGENT);
          if (__all(f >= s)) break;
        }
      }
      // ---- per-wave reload of its 2KB window, parity (s-1)&1 ----
      {
        const uint64_t* hsrc =
            (const uint64_t*)(hb + (size_t)((s - 1) & 1) * BB * NU);
        const int rb = lane >> 3;                 // batch 0..7
        const int c0 = 32 * w + (lane & 7) * 4;   // u64 col in [32w, 32w+32)
        const uint64_t* p = hsrc + ((size_t)(b0 + rb) << 8) + c0;
        uint64_t v0 = __hip_atomic_load(p + 0, __ATOMIC_RELAXED, __HIP_MEMORY_SCOPE_AGENT);
        uint64_t v1 = __hip_atomic_load(p + 1, __ATOMIC_RELAXED, __HIP_MEMORY_SCOPE_AGENT);
        uint64_t v2 = __hip_atomic_load(p + 2, __ATOMIC_RELAXED, __HIP_MEMORY_SCOPE_AGENT);
        uint64_t v3 = __hip_atomic_load(p + 3, __ATOMIC_RELAXED, __HIP_MEMORY_SCOPE_AGENT);
        uint64_t* d = (uint64_t*)&hS[rb][c0 * 2];
        d[0] = v0; d[1] = v1; d[2] = v2; d[3] = v3;
      }
      // ds_write -> ds_read (cross-lane, same wave): explicit fence (rule #18)
      asm volatile("s_waitcnt lgkmcnt(0)" ::: "memory");
      __builtin_amdgcn_sched_barrier(0);
    }

    float az[8], ar[8], ah[8];
    #pragma unroll
    for (int b = 0; b < 8; ++b) { az[b] = 0.f; ar[b] = 0.f; ah[b] = 0.f; }
    #pragma unroll
    for (int q = 0; q < 8; ++q) {
      #pragma unroll
      for (int b = 0; b < 8; ++b) {
        float4 hv = *(const float4*)&hS[b][kb0 + q * 4];   // 2-addr broadcast
        az[b] = fmaf(Uz_r[q*4+0], hv.x, az[b]); az[b] = fmaf(Uz_r[q*4+1], hv.y, az[b]);
        az[b] = fmaf(Uz_r[q*4+2], hv.z, az[b]); az[b] = fmaf(Uz_r[q*4+3], hv.w, az[b]);
        ar[b] = fmaf(Ur_r[q*4+0], hv.x, ar[b]); ar[b] = fmaf(Ur_r[q*4+1], hv.y, ar[b]);
        ar[b] = fmaf(Ur_r[q*4+2], hv.z, ar[b]); ar[b] = fmaf(Ur_r[q*4+3], hv.w, ar[b]);
        ah[b] = fmaf(Uh_r[q*4+0], hv.x, ah[b]); ah[b] = fmaf(Uh_r[q*4+1], hv.y, ah[b]);
        ah[b] = fmaf(Uh_r[q*4+2], hv.z, ah[b]); ah[b] = fmaf(Uh_r[q*4+3], hv.w, ah[b]);
      }
    }
    #pragma unroll
    for (int b = 0; b < 8; ++b) {
      red[0][b][ks][u] = az[b];
      red[1][b][ks][u] = ar[b];
      red[2][b][ks][u] = ah[b];
    }
    __syncthreads();                       // sync1: reduction join
    float hn = 0.f;
    if (tid < 256) {
      float rz = 0.f, rr = 0.f, rh = 0.f;
      #pragma unroll
      for (int q2 = 0; q2 < 16; ++q2) {
        rz += red[0][eb][q2][eu];
        rr += red[1][eb][q2][eu];
        rh += red[2][eb][q2][eu];
      }
      const float z  = 1.f / (1.f + __expf(-(xz + rz + brz)));
      const float r  = 1.f / (1.f + __expf(-(xr + rr + brr)));
      const float hh = tanhf(xh + r * (rh + brh));
      hn = z * hprev + (1.f - z) * hh;
      hprev = hn;
      // h publish: relaxed agent store (published by this block's release)
      __hip_atomic_store(hb + ((size_t)(s & 1) * BB + bg) * NU + u0 + eu, hn,
                         __ATOMIC_RELAXED, __HIP_MEMORY_SCOPE_AGENT);
      // prefetch next step's xw: hides under sync2 + release + poll
      if (s < TT - 1) {
        const int tn = dir ? (TT - 2 - s) : (s + 1);
        const float* xp = xwd + ((size_t)tn * BB + bg) * G3 + u0 + eu;
        xz = xp[0]; xr = xp[512]; xh = xp[1024];
      }
    }
    if (s == TT - 1) {
      if (tid < 256) {
        out[((size_t)bg * TT + t) * 1024 + (size_t)dir * NU + u0 + eu] = hn;
        state[(size_t)bg * 1024 + (size_t)dir * NU + u0 + eu] = hn;
      }
    } else {
      __syncthreads();                     // sync2: all h stores drained to L2
      if (tid == 0) {
        // RELEASE-STORE to PRIVATE slot: wbl2 publishes this block's h, then
        // the flag lands. 16 parallel slots -> no RMW serialization (v4-proven).
        __hip_atomic_store(flags + ublk, s + 1, __ATOMIC_RELEASE,
                           __HIP_MEMORY_SCOPE_AGENT);
      }
      if (tid < 256) {
        // out store in flight during next step's poll/compute
        out[((size_t)bg * TT + t) * 1024 + (size_t)dir * NU + u0 + eu] = hn;
      }
    }
  }
}

extern "C" void kernel_launch(void* const* d_in, const int* in_sizes, int n_in,
                              void* d_out, int out_size, void* d_ws, size_t ws_size,
                              hipStream_t stream) {
  (void)in_sizes; (void)n_in; (void)out_size; (void)ws_size;
  const int*   tokens = (const int*)d_in[0];
  const float* emb    = (const float*)d_in[1];
  const float* Wf     = (const float*)d_in[2];
  const float* Uf     = (const float*)d_in[3];
  const float* bf     = (const float*)d_in[4];
  const float* Wb     = (const float*)d_in[5];
  const float* Ub     = (const float*)d_in[6];
  const float* bb     = (const float*)d_in[7];
  float* ws = (float*)d_ws;
  float* xw = ws;
  float* hb = ws + XW_FLOATS;
  int*   ctr = (int*)(hb + HB_FLOATS);
  float* out = (float*)d_out;
  float* state = out + (size_t)BB * TT * 1024;

  hipMemsetAsync(ctr, 0, 16 * 32 * sizeof(int), stream);
  hipLaunchKernelGGL(k_input_gemm, dim3(24, 512, 2), dim3(256), 0, stream,
                     tokens, emb, Wf, bf, Wb, bb, xw);
  hipLaunchKernelGGL(k_gru, dim3(256), dim3(512), 0, stream,
                     xw, Uf, Ub, bf, bb, hb, ctr, out, state);
}